// Round 13
// baseline (221.553 us; speedup 1.0000x reference)
//
#include <hip/hip_runtime.h>
#include <hip/hip_bf16.h>
#include <math.h>

#define C_N 50000

typedef float f32x16 __attribute__((ext_vector_type(16)));
typedef float f32x4v __attribute__((ext_vector_type(4)));
typedef short bf16x8 __attribute__((ext_vector_type(8)));
typedef unsigned short u16x4 __attribute__((ext_vector_type(4)));
#define VZERO16 {0.f,0.f,0.f,0.f,0.f,0.f,0.f,0.f,0.f,0.f,0.f,0.f,0.f,0.f,0.f,0.f}

// ---- ws layout (float offsets, all multiples of 16) ----
#define OQ     0        // Q[1024]
#define OZ     1024     // z[2048]
#define OH1P   3072     // h1part[2][1024]
#define OY     5120     // ybuf[1024]
#define OCTR   6144     // arrival counter (int)
#define OSUMB  6160     // per-block head sums 512*16
#define OQKB   14352    // qkb bf16 B-fragments: 16384 ushort (8192 floats)
#define OPU    22544    // Pu[16384] fp32 (reduced pool)
#define OPP    38928    // pool partials, bf16: nb*16384 ushort

__device__ __forceinline__ int brev4(int l){
  return ((l&1)<<3)|((l&2)<<1)|((l&4)>>1)|((l&8)>>3);
}

__device__ __forceinline__ float bf2f(unsigned short u){
  unsigned int x = ((unsigned int)u)<<16;
  return __builtin_bit_cast(float, x);
}

// Sum 16 values (f32x16) over 64 lanes; lanes l<16 get total for head brev4(l).
__device__ __forceinline__ float vred16(f32x16 v, int lane){
  float send, got;
#define RS(A,B,M) \
  send = (lane&M)? v[A] : v[B]; \
  got  = __shfl_xor(send, M);   \
  v[A] = ((lane&M)? v[B] : v[A]) + got;
  RS(0,8,1) RS(1,9,1) RS(2,10,1) RS(3,11,1)
  RS(4,12,1) RS(5,13,1) RS(6,14,1) RS(7,15,1)
  RS(0,4,2) RS(1,5,2) RS(2,6,2) RS(3,7,2)
  RS(0,2,4) RS(1,3,4)
  RS(0,1,8)
#undef RS
  float t = v[0];
  t += __shfl_xor(t,16);
  t += __shfl_xor(t,32);
  return t;
}

// ---- 16-output matvec block, NT threads: out_j = sum_i x[i]*W[i*1024+j] ----
template<int IN, int NT>
__device__ __forceinline__ float mv_dot(const float* __restrict__ W,
    const float* __restrict__ x, int tid, int jblk){
  __shared__ float xs[IN];
  __shared__ float red[NT/16][17];
  for (int k=tid;k<IN;k+=NT) xs[k]=x[k];
  __syncthreads();
  int jq = tid&15, iq = tid>>4;
  int j = jblk*16 + jq;
  float acc = 0.f;
#pragma unroll 8
  for (int i=iq;i<IN;i+=NT/16)
    acc = fmaf(xs[i], W[(size_t)i*1024 + j], acc);
  red[iq][jq] = acc;
  __syncthreads();
  float s = 0.f;
  if (tid < 16){
#pragma unroll
    for (int ii=0;ii<NT/16;ii++) s += red[ii][tid];
  }
  return s;
}

// Q = z_prev@Wq + bq; copy z_prev into z[1024:2048]; reset arrival counter
// (ws is not re-poisoned between replays — counter must be reset each call,
// stream order guarantees it lands before hm_fused reads it).
__global__ __launch_bounds__(1024) void hm_mvQ(const float* __restrict__ W,
    const float* __restrict__ x, const float* __restrict__ bq,
    float* __restrict__ Q, float* __restrict__ z, int* __restrict__ ctr){
  if (blockIdx.x==0 && threadIdx.x==0) *ctr = 0;
  float s = mv_dot<1024,1024>(W, x, threadIdx.x, blockIdx.x);
  int tid = threadIdx.x;
  int j0 = blockIdx.x*16;
  if (tid < 16){
    Q[j0+tid] = s + bq[j0+tid];
    z[1024 + j0 + tid] = x[j0 + tid];
  }
}

// qk[i][h] = sum_t Wk[i][h*64+t]*Q[h*64+t]; one wave per row i.
// Writes DIRECTLY in bf16 MFMA B-fragment order:
// flat bf16 idx = (kc*64 + rg*16 + h)*8 + jj with kc=i>>5, rg=(i>>3)&3, jj=i&7.
__global__ __launch_bounds__(256) void hm_qk2(const float* __restrict__ Wk,
    const float* __restrict__ Q, unsigned short* __restrict__ qkb){
  __shared__ float qlds[1024];
  int tid = threadIdx.x;
  for (int k=tid;k<1024;k+=256) qlds[k]=Q[k];
  __syncthreads();
  int w = tid>>6, l = tid&63;
  int i = blockIdx.x*4 + w;
  const float* wr = Wk + (size_t)i*1024 + l;
  f32x16 acc = VZERO16;
#define QKS(k) acc[k] = wr[k*64] * qlds[k*64 + l];
  QKS(0) QKS(1) QKS(2) QKS(3) QKS(4) QKS(5) QKS(6) QKS(7)
  QKS(8) QKS(9) QKS(10) QKS(11) QKS(12) QKS(13) QKS(14) QKS(15)
#undef QKS
  float t = vred16(acc, l);
  if (l < 16){
    int h = brev4(l);
    int kc = i>>5, rg = (i>>3)&3, jj = i&7;
    __hip_bfloat16 b = __float2bfloat16(t);
    qkb[(kc*64 + rg*16 + h)*8 + jj] = *(unsigned short*)&b;
  }
}

#define LD2(AP,KC,FA,FB) \
  FA = *(const float4*)((AP)+(KC)*32); \
  FB = *(const float4*)((AP)+(KC)*32+4);
#define CVT8(FA,FB,AV) { \
  __hip_bfloat16 c0=__float2bfloat16(FA.x),c1=__float2bfloat16(FA.y); \
  __hip_bfloat16 c2=__float2bfloat16(FA.z),c3=__float2bfloat16(FA.w); \
  __hip_bfloat16 c4=__float2bfloat16(FB.x),c5=__float2bfloat16(FB.y); \
  __hip_bfloat16 c6=__float2bfloat16(FB.z),c7=__float2bfloat16(FB.w); \
  AV[0]=*(short*)&c0; AV[1]=*(short*)&c1; AV[2]=*(short*)&c2; AV[3]=*(short*)&c3; \
  AV[4]=*(short*)&c4; AV[5]=*(short*)&c5; AV[6]=*(short*)&c6; AV[7]=*(short*)&c7; }

// Fused scores(MFMA)+exp+pool with LDS tile staging (R11 structure) PLUS
// in-kernel cross-block partial reduction (replaces hm_predA):
//   epilogue: store bf16 partials -> threadfence -> atomicAdd arrival ->
//   spin until all gridDim.x blocks arrived (grid <=512 = 2 blocks/CU x
//   256 CU, all co-resident so progress is guaranteed; NOT the 25us/sync
//   cooperative path) -> each block reduces a fixed 32-elem slice of all
//   partials into fp32 Pu (fixed b-order: deterministic output).
__global__ __launch_bounds__(256,2) void hm_fused(const float* __restrict__ nodes,
    const unsigned short* __restrict__ qkb, unsigned short* __restrict__ parts,
    float* __restrict__ sumpb, float* __restrict__ Pu, int* __restrict__ ctr){
  extern __shared__ float tile[];           // [16][1028]
  __shared__ float part[4][16][17];
  __shared__ float eb[16][16];
  __shared__ float rsum[8][32];
  const int tid = threadIdx.x, w = tid>>6, l = tid&63;
  const int rowA = l&15, kgrp = l>>4;
  const int r_ = tid>>4, h_ = tid&15;

  bf16x8 bq0,bq1,bq2,bq3,bq4,bq5,bq6,bq7;
  {
    const bf16x8* qb = (const bf16x8*)qkb;
    const int o = w*8*64 + l;
    bq0=qb[o]; bq1=qb[o+64]; bq2=qb[o+128]; bq3=qb[o+192];
    bq4=qb[o+256]; bq5=qb[o+320]; bq6=qb[o+384]; bq7=qb[o+448];
  }
  f32x16 a0 = VZERO16, a1 = VZERO16, a2 = VZERO16, a3 = VZERO16;
  float ssum = 0.f;
  const int stride = gridDim.x;

  int cb = blockIdx.x;
  float4 p0a,p0b,p1a,p1b,p2a,p2b,p3a,p3b,p4a,p4b,p5a,p5b,p6a,p6b,p7a,p7b;
  {
    const float* ap = nodes + ((size_t)(cb*16 + rowA))*1024 + w*256 + kgrp*8;
    LD2(ap,0,p0a,p0b) LD2(ap,1,p1a,p1b) LD2(ap,2,p2a,p2b) LD2(ap,3,p3a,p3b)
    LD2(ap,4,p4a,p4b) LD2(ap,5,p5a,p5b) LD2(ap,6,p6a,p6b) LD2(ap,7,p7a,p7b)
  }
  float* tw = tile + rowA*1028 + w*256 + kgrp*8;

  for (; cb < 3125; cb += stride){
    // park this cb's fp32 fragments in LDS (wave-private columns, no barrier)
    *(float4*)(tw+0*32) = p0a; *(float4*)(tw+0*32+4) = p0b;
    *(float4*)(tw+1*32) = p1a; *(float4*)(tw+1*32+4) = p1b;
    *(float4*)(tw+2*32) = p2a; *(float4*)(tw+2*32+4) = p2b;
    *(float4*)(tw+3*32) = p3a; *(float4*)(tw+3*32+4) = p3b;
    *(float4*)(tw+4*32) = p4a; *(float4*)(tw+4*32+4) = p4b;
    *(float4*)(tw+5*32) = p5a; *(float4*)(tw+5*32+4) = p5b;
    *(float4*)(tw+6*32) = p6a; *(float4*)(tw+6*32+4) = p6b;
    *(float4*)(tw+7*32) = p7a; *(float4*)(tw+7*32+4) = p7b;
    bf16x8 av0,av1,av2,av3,av4,av5,av6,av7;
    CVT8(p0a,p0b,av0) CVT8(p1a,p1b,av1) CVT8(p2a,p2b,av2) CVT8(p3a,p3b,av3)
    CVT8(p4a,p4b,av4) CVT8(p5a,p5b,av5) CVT8(p6a,p6b,av6) CVT8(p7a,p7b,av7)
    f32x4v D0 = {0.f,0.f,0.f,0.f};
    f32x4v D1 = {0.f,0.f,0.f,0.f};
    D0 = __builtin_amdgcn_mfma_f32_16x16x32_bf16(av0, bq0, D0, 0,0,0);
    D1 = __builtin_amdgcn_mfma_f32_16x16x32_bf16(av1, bq1, D1, 0,0,0);
    D0 = __builtin_amdgcn_mfma_f32_16x16x32_bf16(av2, bq2, D0, 0,0,0);
    D1 = __builtin_amdgcn_mfma_f32_16x16x32_bf16(av3, bq3, D1, 0,0,0);
    D0 = __builtin_amdgcn_mfma_f32_16x16x32_bf16(av4, bq4, D0, 0,0,0);
    D1 = __builtin_amdgcn_mfma_f32_16x16x32_bf16(av5, bq5, D1, 0,0,0);
    D0 = __builtin_amdgcn_mfma_f32_16x16x32_bf16(av6, bq6, D0, 0,0,0);
    D1 = __builtin_amdgcn_mfma_f32_16x16x32_bf16(av7, bq7, D1, 0,0,0);
    {
      int cbn = cb + stride; if (cbn >= 3125) cbn = cb;
      const float* apn = nodes + ((size_t)(cbn*16 + rowA))*1024 + w*256 + kgrp*8;
      LD2(apn,0,p0a,p0b) LD2(apn,1,p1a,p1b) LD2(apn,2,p2a,p2b) LD2(apn,3,p3a,p3b)
      LD2(apn,4,p4a,p4b) LD2(apn,5,p5a,p5b) LD2(apn,6,p6a,p6b) LD2(apn,7,p7a,p7b)
    }
#pragma unroll
    for (int i=0;i<4;i++) part[w][kgrp*4+i][rowA] = D0[i] + D1[i];
    __syncthreads();                       // barrier1: part ready
    {
      float s = part[0][r_][h_]+part[1][r_][h_]+part[2][r_][h_]+part[3][r_][h_];
      eb[r_][h_] = __expf(s * 0.125f);
    }
    __syncthreads();                       // barrier2: eb ready
    if (tid < 16){
#pragma unroll
      for (int rr=0;rr<16;rr++) ssum += eb[rr][tid];
    }
    const float* tr = tile + w*256 + l*4;
#pragma unroll 4
    for (int r=0;r<16;r++){
      float4 nv = *(const float4*)(tr + r*1028);
      f32x16 u = *(const f32x16*)&eb[r][0];
      a0 += u*nv.x; a1 += u*nv.y; a2 += u*nv.z; a3 += u*nv.w;
    }
  }
  // ---- epilogue: bf16 partials ----
  unsigned short* p = parts + (size_t)blockIdx.x*16384 + w*256 + l*4;
#pragma unroll
  for (int h=0;h<16;h++){
    __hip_bfloat16 b0=__float2bfloat16(a0[h]), b1=__float2bfloat16(a1[h]);
    __hip_bfloat16 b2=__float2bfloat16(a2[h]), b3=__float2bfloat16(a3[h]);
    u16x4 o;
    o[0]=*(unsigned short*)&b0; o[1]=*(unsigned short*)&b1;
    o[2]=*(unsigned short*)&b2; o[3]=*(unsigned short*)&b3;
    *(u16x4*)(p + h*1024) = o;
  }
  if (tid < 16) sumpb[blockIdx.x*16 + tid] = ssum;
  // ---- arrival barrier ----
  __threadfence();                         // flush this thread's stores
  __syncthreads();                         // all threads fenced
  if (tid == 0){
    atomicAdd(ctr, 1);
    while (__hip_atomic_load(ctr, __ATOMIC_ACQUIRE, __HIP_MEMORY_SCOPE_AGENT)
           < (int)gridDim.x)
      __builtin_amdgcn_s_sleep(2);
  }
  __syncthreads();
  __threadfence();
  // ---- deterministic reduce: fixed 32-elem slices, fixed b-order ----
  const int nb = gridDim.x;
  for (int j0 = blockIdx.x*32; j0 < 16384; j0 += nb*32){
    int jj = tid&31, bgrp = tid>>5;        // 8 b-groups x 32 j
    float s = 0.f;
    for (int b=bgrp; b<nb; b+=8)
      s += bf2f(parts[(size_t)b*16384 + j0 + jj]);
    rsum[bgrp][jj] = s;
    __syncthreads();
    if (tid < 32){
      float t = 0.f;
#pragma unroll
      for (int g=0; g<8; g++) t += rsum[g][tid];
      Pu[j0 + tid] = t;
    }
    __syncthreads();
  }
}

// z[j] = (Pu[h]·Wv[:,j])/S[h] + bv[j]; S[h] reduced inline from sumpb.
__global__ __launch_bounds__(1024) void hm_mvV(const float* __restrict__ W,
    const float* __restrict__ Pu, const float* __restrict__ sumpb,
    const float* __restrict__ bv, float* __restrict__ z, int nb){
  __shared__ float xs[1024];
  __shared__ float red[64][17];
  __shared__ float ssl[16];
  const int tid = threadIdx.x;
  const int hh = blockIdx.x>>2;
  float sacc = 0.f;
  for (int b=tid; b<nb; b+=1024) sacc += sumpb[b*16 + hh];
#pragma unroll
  for (int m=1;m<64;m<<=1) sacc += __shfl_xor(sacc, m);
  if ((tid&63)==0) ssl[tid>>6] = sacc;
  xs[tid] = Pu[hh*1024 + tid];
  __syncthreads();
  int jq = tid&15, iq = tid>>4;
  int j = blockIdx.x*16 + jq;
  float acc = 0.f;
#pragma unroll 8
  for (int i=iq;i<1024;i+=64)
    acc = fmaf(xs[i], W[(size_t)i*1024 + j], acc);
  red[iq][jq] = acc;
  __syncthreads();
  if (tid < 16){
    float s = 0.f;
#pragma unroll
    for (int ii=0;ii<64;ii++) s += red[ii][tid];
    float S = 0.f;
#pragma unroll
    for (int q=0;q<16;q++) S += ssl[q];
    int jo = blockIdx.x*16 + tid;
    z[jo] = s / S + bv[jo];
  }
}

// W1 partials, grid (64,2): iseg halves of the 2048-row W1.
__global__ __launch_bounds__(1024) void hm_mvW1(const float* __restrict__ W,
    const float* __restrict__ z, float* __restrict__ h1part){
  __shared__ float xs[1024];
  __shared__ float red[64][17];
  const int tid = threadIdx.x;
  const int iseg = blockIdx.y;
  xs[tid] = z[iseg*1024 + tid];
  __syncthreads();
  int jq = tid&15, iq = tid>>4;
  int j = blockIdx.x*16 + jq;
  const float* Wp = W + (size_t)(iseg*1024)*1024;
  float acc = 0.f;
#pragma unroll
  for (int k=0;k<16;k++){
    int i = iq + 64*k;
    acc = fmaf(xs[i], Wp[(size_t)i*1024 + j], acc);
  }
  red[iq][jq] = acc;
  __syncthreads();
  if (tid < 16){
    float s = 0.f;
#pragma unroll
    for (int ii=0;ii<64;ii++) s += red[ii][tid];
    h1part[iseg*1024 + blockIdx.x*16 + tid] = s;
  }
}

// mvW2: stage hb = GELU(h1part[0]+h1part[1]+b1), then 1024-dot + b2.
__global__ __launch_bounds__(1024) void hm_mvW2(const float* __restrict__ W,
    const float* __restrict__ h1part, const float* __restrict__ b1,
    const float* __restrict__ b2, float* __restrict__ y){
  __shared__ float xs[1024];
  __shared__ float red[64][17];
  const int tid = threadIdx.x;
  {
    float s = b1[tid] + h1part[tid] + h1part[1024 + tid];
    xs[tid] = 0.5f * s * (1.0f + erff(s * 0.70710678118654752f));
  }
  __syncthreads();
  int jq = tid&15, iq = tid>>4;
  int j = blockIdx.x*16 + jq;
  float acc = 0.f;
#pragma unroll
  for (int k=0;k<16;k++){
    int i = iq + 64*k;
    acc = fmaf(xs[i], W[(size_t)i*1024 + j], acc);
  }
  red[iq][jq] = acc;
  __syncthreads();
  if (tid < 16){
    float s = 0.f;
#pragma unroll
    for (int ii=0;ii<64;ii++) s += red[ii][tid];
    int jo = blockIdx.x*16 + tid;
    y[jo] = s + b2[jo];
  }
}

__global__ __launch_bounds__(256) void hm_rms(const float* __restrict__ y,
    const float* __restrict__ scale, float* __restrict__ out){
  __shared__ float red[4];
  __shared__ float msv;
  int tid = threadIdx.x;
  float local = 0.f;
  for (int j=tid;j<1024;j+=256){ float t = y[j]; local = fmaf(t,t,local); }
#pragma unroll
  for (int m=1;m<64;m<<=1) local += __shfl_xor(local, m);
  if ((tid&63)==0) red[tid>>6] = local;
  __syncthreads();
  if (tid==0){
    float s = red[0]+red[1]+red[2]+red[3];
    msv = rsqrtf(s*(1.0f/1024.0f) + 1e-6f);
  }
  __syncthreads();
  float r = msv;
  for (int j=tid;j<1024;j+=256) out[j] = scale[j]*y[j]*r;
}

extern "C" void kernel_launch(void* const* d_in, const int* in_sizes, int n_in,
                              void* d_out, int out_size, void* d_ws, size_t ws_size,
                              hipStream_t stream){
  const float* nodes  = (const float*)d_in[0];
  const float* z_prev = (const float*)d_in[1];
  const float* Wq = (const float*)d_in[2];
  const float* bq = (const float*)d_in[3];
  const float* Wk = (const float*)d_in[4];
  // d_in[5] = bk — cancels in softmax, unused
  const float* Wv = (const float*)d_in[6];
  const float* bv = (const float*)d_in[7];
  const float* W1 = (const float*)d_in[8];
  const float* b1 = (const float*)d_in[9];
  const float* W2 = (const float*)d_in[10];
  const float* b2 = (const float*)d_in[11];
  const float* scale = (const float*)d_in[12];
  float* ws  = (float*)d_ws;
  float* out = (float*)d_out;

  float* Qv     = ws + OQ;
  float* z      = ws + OZ;
  float* h1part = ws + OH1P;
  float* ybuf   = ws + OY;
  int*   ctr    = (int*)(ws + OCTR);
  float* sumb   = ws + OSUMB;
  unsigned short* qkb = (unsigned short*)(ws + OQKB);
  float* Pu     = ws + OPU;
  unsigned short* pp  = (unsigned short*)(ws + OPP);

  size_t need0 = (size_t)OPP*4;
  int nbp = 1;
  if (ws_size > need0 + 32768) nbp = (int)((ws_size - need0)/32768);
  if (nbp > 512) nbp = 512;   // 2 blocks/CU x 256 CU: co-residency for the
  if (nbp < 1) nbp = 1;       // in-kernel arrival barrier

  const size_t tile_bytes = 16*1028*sizeof(float);  // 65792

  hm_mvQ   <<<64,  1024, 0, stream>>>(Wq, z_prev, bq, Qv, z, ctr);
  hm_qk2   <<<256, 256, 0, stream>>>(Wk, Qv, qkb);
  hm_fused <<<nbp, 256, tile_bytes, stream>>>(nodes, qkb, pp, sumb, Pu, ctr);
  hm_mvV   <<<64,  1024, 0, stream>>>(Wv, Pu, sumb, bv, z, nbp);
  hm_mvW1  <<<dim3(64,2), 1024, 0, stream>>>(W1, z, h1part);
  hm_mvW2  <<<64,  1024, 0, stream>>>(W2, h1part, b1, b2, ybuf);
  hm_rms   <<<1,   256, 0, stream>>>(ybuf, scale, out);
}

// Round 14
// 180.414 us; speedup vs baseline: 1.2280x; 1.2280x over previous
//
#include <hip/hip_runtime.h>
#include <hip/hip_bf16.h>
#include <math.h>

#define C_N 50000

typedef float f32x16 __attribute__((ext_vector_type(16)));
typedef float f32x4v __attribute__((ext_vector_type(4)));
typedef short bf16x8 __attribute__((ext_vector_type(8)));
typedef unsigned short u16x4 __attribute__((ext_vector_type(4)));
#define VZERO16 {0.f,0.f,0.f,0.f,0.f,0.f,0.f,0.f,0.f,0.f,0.f,0.f,0.f,0.f,0.f,0.f}

// ---- ws layout (float offsets, all multiples of 16) ----
#define OQ     0        // Q[1024]
#define OZB    1024     // zbuf[1024]
#define OH1    2048     // h1buf[1024]
#define OYB    3072     // ybuf[1024]
#define OCTR   4096     // ctr[3] barriers (ints)
#define OSUMB  4112     // per-block head sums 512*16
#define OQKB   12304    // qkb bf16 B-fragments: 16384 ushort (8192 floats)
#define OPP2   20496    // pp2 bf16: 32*16384 ushort (262144 float slots)
#define OPP    282640   // pool partials, bf16: nb*16384 ushort

__device__ __forceinline__ int brev4(int l){
  return ((l&1)<<3)|((l&2)<<1)|((l&4)>>1)|((l&8)>>3);
}

__device__ __forceinline__ float bf2f(unsigned short u){
  unsigned int x = ((unsigned int)u)<<16;
  return __builtin_bit_cast(float, x);
}

// Sum 16 values (f32x16) over 64 lanes; lanes l<16 get total for head brev4(l).
__device__ __forceinline__ float vred16(f32x16 v, int lane){
  float send, got;
#define RS(A,B,M) \
  send = (lane&M)? v[A] : v[B]; \
  got  = __shfl_xor(send, M);   \
  v[A] = ((lane&M)? v[B] : v[A]) + got;
  RS(0,8,1) RS(1,9,1) RS(2,10,1) RS(3,11,1)
  RS(4,12,1) RS(5,13,1) RS(6,14,1) RS(7,15,1)
  RS(0,4,2) RS(1,5,2) RS(2,6,2) RS(3,7,2)
  RS(0,2,4) RS(1,3,4)
  RS(0,1,8)
#undef RS
  float t = v[0];
  t += __shfl_xor(t,16);
  t += __shfl_xor(t,32);
  return t;
}

// Cross-block arrival barrier (R13-verified pattern; 64 co-resident blocks).
__device__ __forceinline__ void gbar(int* c, int n){
  __syncthreads();
  __threadfence();
  if (threadIdx.x == 0){
    atomicAdd(c, 1);
    while (__hip_atomic_load(c, __ATOMIC_RELAXED, __HIP_MEMORY_SCOPE_AGENT) < n)
      __builtin_amdgcn_s_sleep(1);
  }
  __syncthreads();
  __threadfence();   // acquire: subsequent loads see other blocks' stores
}

// ---- 16-output matvec block, NT threads: out_j = sum_i x[i]*W[i*1024+j] ----
template<int IN, int NT>
__device__ __forceinline__ float mv_dot(const float* __restrict__ W,
    const float* __restrict__ x, int tid, int jblk){
  __shared__ float xs[IN];
  __shared__ float red[NT/16][17];
  for (int k=tid;k<IN;k+=NT) xs[k]=x[k];
  __syncthreads();
  int jq = tid&15, iq = tid>>4;
  int j = jblk*16 + jq;
  float acc = 0.f;
#pragma unroll 8
  for (int i=iq;i<IN;i+=NT/16)
    acc = fmaf(xs[i], W[(size_t)i*1024 + j], acc);
  red[iq][jq] = acc;
  __syncthreads();
  float s = 0.f;
  if (tid < 16){
#pragma unroll
    for (int ii=0;ii<NT/16;ii++) s += red[ii][tid];
  }
  return s;
}

// Q = z_prev@Wq + bq; resets the 3 tail barrier counters (ws not re-poisoned
// between replays; stream order puts this before hm_tail reads them).
__global__ __launch_bounds__(1024) void hm_mvQ(const float* __restrict__ W,
    const float* __restrict__ x, const float* __restrict__ bq,
    float* __restrict__ Q, int* __restrict__ ctr){
  if (blockIdx.x==0 && threadIdx.x<3) ctr[threadIdx.x] = 0;
  float s = mv_dot<1024,1024>(W, x, threadIdx.x, blockIdx.x);
  int tid = threadIdx.x;
  int j0 = blockIdx.x*16;
  if (tid < 16) Q[j0+tid] = s + bq[j0+tid];
}

// qk[i][h] = sum_t Wk[i][h*64+t]*Q[h*64+t]; one wave per row i.
// Writes DIRECTLY in bf16 MFMA B-fragment order:
// flat bf16 idx = (kc*64 + rg*16 + h)*8 + jj with kc=i>>5, rg=(i>>3)&3, jj=i&7.
__global__ __launch_bounds__(256) void hm_qk2(const float* __restrict__ Wk,
    const float* __restrict__ Q, unsigned short* __restrict__ qkb){
  __shared__ float qlds[1024];
  int tid = threadIdx.x;
  for (int k=tid;k<1024;k+=256) qlds[k]=Q[k];
  __syncthreads();
  int w = tid>>6, l = tid&63;
  int i = blockIdx.x*4 + w;
  const float* wr = Wk + (size_t)i*1024 + l;
  f32x16 acc = VZERO16;
#define QKS(k) acc[k] = wr[k*64] * qlds[k*64 + l];
  QKS(0) QKS(1) QKS(2) QKS(3) QKS(4) QKS(5) QKS(6) QKS(7)
  QKS(8) QKS(9) QKS(10) QKS(11) QKS(12) QKS(13) QKS(14) QKS(15)
#undef QKS
  float t = vred16(acc, l);
  if (l < 16){
    int h = brev4(l);
    int kc = i>>5, rg = (i>>3)&3, jj = i&7;
    __hip_bfloat16 b = __float2bfloat16(t);
    qkb[(kc*64 + rg*16 + h)*8 + jj] = *(unsigned short*)&b;
  }
}

#define LD2(AP,KC,FA,FB) \
  FA = *(const float4*)((AP)+(KC)*32); \
  FB = *(const float4*)((AP)+(KC)*32+4);
#define CVT8(FA,FB,AV) { \
  __hip_bfloat16 c0=__float2bfloat16(FA.x),c1=__float2bfloat16(FA.y); \
  __hip_bfloat16 c2=__float2bfloat16(FA.z),c3=__float2bfloat16(FA.w); \
  __hip_bfloat16 c4=__float2bfloat16(FB.x),c5=__float2bfloat16(FB.y); \
  __hip_bfloat16 c6=__float2bfloat16(FB.z),c7=__float2bfloat16(FB.w); \
  AV[0]=*(short*)&c0; AV[1]=*(short*)&c1; AV[2]=*(short*)&c2; AV[3]=*(short*)&c3; \
  AV[4]=*(short*)&c4; AV[5]=*(short*)&c5; AV[6]=*(short*)&c6; AV[7]=*(short*)&c7; }

// Fused scores(MFMA)+exp+pool — EXACT R11 structure (87.5us config).
// No barrier/reduce epilogue here: R13 showed any added epilogue state
// spills the 64-VGPR pool accumulators (VGPR 215->108, 256us).
__global__ __launch_bounds__(256,2) void hm_fused(const float* __restrict__ nodes,
    const unsigned short* __restrict__ qkb, unsigned short* __restrict__ parts,
    float* __restrict__ sumpb){
  extern __shared__ float tile[];           // [16][1028]
  __shared__ float part[4][16][17];
  __shared__ float eb[16][16];
  const int tid = threadIdx.x, w = tid>>6, l = tid&63;
  const int rowA = l&15, kgrp = l>>4;
  const int r_ = tid>>4, h_ = tid&15;

  bf16x8 bq0,bq1,bq2,bq3,bq4,bq5,bq6,bq7;
  {
    const bf16x8* qb = (const bf16x8*)qkb;
    const int o = w*8*64 + l;
    bq0=qb[o]; bq1=qb[o+64]; bq2=qb[o+128]; bq3=qb[o+192];
    bq4=qb[o+256]; bq5=qb[o+320]; bq6=qb[o+384]; bq7=qb[o+448];
  }
  f32x16 a0 = VZERO16, a1 = VZERO16, a2 = VZERO16, a3 = VZERO16;
  float ssum = 0.f;
  const int stride = gridDim.x;

  int cb = blockIdx.x;
  float4 p0a,p0b,p1a,p1b,p2a,p2b,p3a,p3b,p4a,p4b,p5a,p5b,p6a,p6b,p7a,p7b;
  {
    const float* ap = nodes + ((size_t)(cb*16 + rowA))*1024 + w*256 + kgrp*8;
    LD2(ap,0,p0a,p0b) LD2(ap,1,p1a,p1b) LD2(ap,2,p2a,p2b) LD2(ap,3,p3a,p3b)
    LD2(ap,4,p4a,p4b) LD2(ap,5,p5a,p5b) LD2(ap,6,p6a,p6b) LD2(ap,7,p7a,p7b)
  }
  float* tw = tile + rowA*1028 + w*256 + kgrp*8;

  for (; cb < 3125; cb += stride){
    *(float4*)(tw+0*32) = p0a; *(float4*)(tw+0*32+4) = p0b;
    *(float4*)(tw+1*32) = p1a; *(float4*)(tw+1*32+4) = p1b;
    *(float4*)(tw+2*32) = p2a; *(float4*)(tw+2*32+4) = p2b;
    *(float4*)(tw+3*32) = p3a; *(float4*)(tw+3*32+4) = p3b;
    *(float4*)(tw+4*32) = p4a; *(float4*)(tw+4*32+4) = p4b;
    *(float4*)(tw+5*32) = p5a; *(float4*)(tw+5*32+4) = p5b;
    *(float4*)(tw+6*32) = p6a; *(float4*)(tw+6*32+4) = p6b;
    *(float4*)(tw+7*32) = p7a; *(float4*)(tw+7*32+4) = p7b;
    bf16x8 av0,av1,av2,av3,av4,av5,av6,av7;
    CVT8(p0a,p0b,av0) CVT8(p1a,p1b,av1) CVT8(p2a,p2b,av2) CVT8(p3a,p3b,av3)
    CVT8(p4a,p4b,av4) CVT8(p5a,p5b,av5) CVT8(p6a,p6b,av6) CVT8(p7a,p7b,av7)
    f32x4v D0 = {0.f,0.f,0.f,0.f};
    f32x4v D1 = {0.f,0.f,0.f,0.f};
    D0 = __builtin_amdgcn_mfma_f32_16x16x32_bf16(av0, bq0, D0, 0,0,0);
    D1 = __builtin_amdgcn_mfma_f32_16x16x32_bf16(av1, bq1, D1, 0,0,0);
    D0 = __builtin_amdgcn_mfma_f32_16x16x32_bf16(av2, bq2, D0, 0,0,0);
    D1 = __builtin_amdgcn_mfma_f32_16x16x32_bf16(av3, bq3, D1, 0,0,0);
    D0 = __builtin_amdgcn_mfma_f32_16x16x32_bf16(av4, bq4, D0, 0,0,0);
    D1 = __builtin_amdgcn_mfma_f32_16x16x32_bf16(av5, bq5, D1, 0,0,0);
    D0 = __builtin_amdgcn_mfma_f32_16x16x32_bf16(av6, bq6, D0, 0,0,0);
    D1 = __builtin_amdgcn_mfma_f32_16x16x32_bf16(av7, bq7, D1, 0,0,0);
    {
      int cbn = cb + stride; if (cbn >= 3125) cbn = cb;
      const float* apn = nodes + ((size_t)(cbn*16 + rowA))*1024 + w*256 + kgrp*8;
      LD2(apn,0,p0a,p0b) LD2(apn,1,p1a,p1b) LD2(apn,2,p2a,p2b) LD2(apn,3,p3a,p3b)
      LD2(apn,4,p4a,p4b) LD2(apn,5,p5a,p5b) LD2(apn,6,p6a,p6b) LD2(apn,7,p7a,p7b)
    }
#pragma unroll
    for (int i=0;i<4;i++) part[w][kgrp*4+i][rowA] = D0[i] + D1[i];
    __syncthreads();                       // barrier1: part ready
    {
      float s = part[0][r_][h_]+part[1][r_][h_]+part[2][r_][h_]+part[3][r_][h_];
      eb[r_][h_] = __expf(s * 0.125f);
    }
    __syncthreads();                       // barrier2: eb ready
    if (tid < 16){
#pragma unroll
      for (int rr=0;rr<16;rr++) ssum += eb[rr][tid];
    }
    const float* tr = tile + w*256 + l*4;
#pragma unroll 4
    for (int r=0;r<16;r++){
      float4 nv = *(const float4*)(tr + r*1028);
      f32x16 u = *(const f32x16*)&eb[r][0];
      a0 += u*nv.x; a1 += u*nv.y; a2 += u*nv.z; a3 += u*nv.w;
    }
  }
  unsigned short* p = parts + (size_t)blockIdx.x*16384 + w*256 + l*4;
#pragma unroll
  for (int h=0;h<16;h++){
    __hip_bfloat16 b0=__float2bfloat16(a0[h]), b1=__float2bfloat16(a1[h]);
    __hip_bfloat16 b2=__float2bfloat16(a2[h]), b3=__float2bfloat16(a3[h]);
    u16x4 o;
    o[0]=*(unsigned short*)&b0; o[1]=*(unsigned short*)&b1;
    o[2]=*(unsigned short*)&b2; o[3]=*(unsigned short*)&b3;
    *(u16x4*)(p + h*1024) = o;
  }
  if (tid < 16) sumpb[blockIdx.x*16 + tid] = ssum;
}

// Stage A: pp2[y][j] = sum of 16 bf16 partials; u16x4 per thread (8B loads)
__global__ __launch_bounds__(256) void hm_predA(const unsigned short* __restrict__ parts,
    unsigned short* __restrict__ pp2, int nb){
  int j4 = blockIdx.x*256 + threadIdx.x;
  int b0 = blockIdx.y*16;
  int b1 = b0+16 < nb ? b0+16 : nb;
  float s0=0.f, s1=0.f, s2=0.f, s3=0.f;
  for (int b=b0;b<b1;b++){
    u16x4 v = *(const u16x4*)&parts[(size_t)b*16384 + j4*4];
    s0 += bf2f(v[0]); s1 += bf2f(v[1]); s2 += bf2f(v[2]); s3 += bf2f(v[3]);
  }
  __hip_bfloat16 r0=__float2bfloat16(s0), r1=__float2bfloat16(s1);
  __hip_bfloat16 r2=__float2bfloat16(s2), r3=__float2bfloat16(s3);
  u16x4 o;
  o[0]=*(unsigned short*)&r0; o[1]=*(unsigned short*)&r1;
  o[2]=*(unsigned short*)&r2; o[3]=*(unsigned short*)&r3;
  *(u16x4*)&pp2[(size_t)blockIdx.y*16384 + j4*4] = o;
}

// Persistent tail: mvV -> [bar] -> mvW1(full 2048-dot)+GELU -> [bar] ->
// mvW2 -> [bar] -> block0 RMS. 64 blocks x 1024 thr (16 waves/block; 64
// blocks over 256 CUs => co-resident, barrier is deadlock-free). All phases
// are low-VGPR matvecs — no spill risk (the R13 lesson: keep barriers away
// from the 215-VGPR fused kernel).
__global__ __launch_bounds__(1024) void hm_tail(const float* __restrict__ Wv,
    const unsigned short* __restrict__ pp2, const float* __restrict__ sumpb,
    const float* __restrict__ bv, const float* __restrict__ z_prev,
    const float* __restrict__ W1, const float* __restrict__ b1,
    const float* __restrict__ W2, const float* __restrict__ b2,
    const float* __restrict__ scale, float* __restrict__ zbuf,
    float* __restrict__ h1buf, float* __restrict__ ybuf,
    float* __restrict__ out, int ny, int nb, int* __restrict__ ctr){
  __shared__ float xs[2048];
  __shared__ float red[64][17];
  __shared__ float ssl[16];
  __shared__ float rr[16];
  __shared__ float msv;
  const int tid = threadIdx.x, bid = blockIdx.x;
  const int jq = tid&15, iq = tid>>4;
  const int j = bid*16 + jq;

  // ---- phase 1: z = Pu[hh]·Wv[:,j]/S + bv ----
  {
    const int hh = bid>>2;
    float sacc = 0.f;
    for (int b=tid; b<nb; b+=1024) sacc += sumpb[b*16 + hh];
#pragma unroll
    for (int m=1;m<64;m<<=1) sacc += __shfl_xor(sacc, m);
    if ((tid&63)==0) ssl[tid>>6] = sacc;
    float s = 0.f;
    for (int y=0;y<ny;y++) s += bf2f(pp2[(size_t)y*16384 + hh*1024 + tid]);
    xs[tid] = s;
    __syncthreads();
    float acc = 0.f;
#pragma unroll 8
    for (int i=iq;i<1024;i+=64)
      acc = fmaf(xs[i], Wv[(size_t)i*1024 + j], acc);
    red[iq][jq] = acc;
    __syncthreads();
    if (tid < 16){
      float s2 = 0.f;
#pragma unroll
      for (int ii=0;ii<64;ii++) s2 += red[ii][tid];
      float S = 0.f;
#pragma unroll
      for (int q=0;q<16;q++) S += ssl[q];
      int jo = bid*16 + tid;
      zbuf[jo] = s2 / S + bv[jo];
    }
  }
  gbar(ctr+0, gridDim.x);
  // ---- phase 2: h1 = GELU(z·W1 + b1), full 2048-dot per output ----
  {
    xs[tid] = zbuf[tid];
    xs[1024 + tid] = z_prev[tid];
    __syncthreads();
    float acc = 0.f;
#pragma unroll 8
    for (int i=iq;i<2048;i+=64)
      acc = fmaf(xs[i], W1[(size_t)i*1024 + j], acc);
    red[iq][jq] = acc;
    __syncthreads();
    if (tid < 16){
      float s = 0.f;
#pragma unroll
      for (int ii=0;ii<64;ii++) s += red[ii][tid];
      int jo = bid*16 + tid;
      s += b1[jo];
      h1buf[jo] = 0.5f * s * (1.0f + erff(s * 0.70710678118654752f));
    }
  }
  gbar(ctr+1, gridDim.x);
  // ---- phase 3: y = h1·W2 + b2 ----
  {
    __syncthreads();                       // xs reuse fence
    xs[tid] = h1buf[tid];
    __syncthreads();
    float acc = 0.f;
#pragma unroll 8
    for (int i=iq;i<1024;i+=64)
      acc = fmaf(xs[i], W2[(size_t)i*1024 + j], acc);
    red[iq][jq] = acc;
    __syncthreads();
    if (tid < 16){
      float s = 0.f;
#pragma unroll
      for (int ii=0;ii<64;ii++) s += red[ii][tid];
      int jo = bid*16 + tid;
      ybuf[jo] = s + b2[jo];
    }
  }
  gbar(ctr+2, gridDim.x);
  // ---- phase 4: block 0 RMSNorm ----
  if (bid == 0){
    float y = ybuf[tid];
    float loc = y*y;
#pragma unroll
    for (int m=1;m<64;m<<=1) loc += __shfl_xor(loc, m);
    if ((tid&63)==0) rr[tid>>6] = loc;
    __syncthreads();
    if (tid==0){
      float s = 0.f;
#pragma unroll
      for (int q=0;q<16;q++) s += rr[q];
      msv = rsqrtf(s*(1.0f/1024.0f) + 1e-6f);
    }
    __syncthreads();
    out[tid] = scale[tid]*y*msv;
  }
}

extern "C" void kernel_launch(void* const* d_in, const int* in_sizes, int n_in,
                              void* d_out, int out_size, void* d_ws, size_t ws_size,
                              hipStream_t stream){
  const float* nodes  = (const float*)d_in[0];
  const float* z_prev = (const float*)d_in[1];
  const float* Wq = (const float*)d_in[2];
  const float* bq = (const float*)d_in[3];
  const float* Wk = (const float*)d_in[4];
  // d_in[5] = bk — cancels in softmax, unused
  const float* Wv = (const float*)d_in[6];
  const float* bv = (const float*)d_in[7];
  const float* W1 = (const float*)d_in[8];
  const float* b1 = (const float*)d_in[9];
  const float* W2 = (const float*)d_in[10];
  const float* b2 = (const float*)d_in[11];
  const float* scale = (const float*)d_in[12];
  float* ws  = (float*)d_ws;
  float* out = (float*)d_out;

  float* Qv     = ws + OQ;
  float* zbuf   = ws + OZB;
  float* h1buf  = ws + OH1;
  float* ybuf   = ws + OYB;
  int*   ctr    = (int*)(ws + OCTR);
  float* sumb   = ws + OSUMB;
  unsigned short* qkb = (unsigned short*)(ws + OQKB);
  unsigned short* pp2 = (unsigned short*)(ws + OPP2);
  unsigned short* pp  = (unsigned short*)(ws + OPP);

  size_t need0 = (size_t)OPP*4;
  int nbp = 1;
  if (ws_size > need0 + 32768) nbp = (int)((ws_size - need0)/32768);
  if (nbp > 512) nbp = 512;
  if (nbp < 1) nbp = 1;
  int ny = (nbp + 15)/16;   // <= 32

  const size_t tile_bytes = 16*1028*sizeof(float);  // 65792

  hm_mvQ   <<<64,  1024, 0, stream>>>(Wq, z_prev, bq, Qv, ctr);
  hm_qk2   <<<256, 256, 0, stream>>>(Wk, Qv, qkb);
  hm_fused <<<nbp, 256, tile_bytes, stream>>>(nodes, qkb, pp, sumb);
  hm_predA <<<dim3(16,ny), 256, 0, stream>>>(pp, pp2, nbp);
  hm_tail  <<<64,  1024, 0, stream>>>(Wv, pp2, sumb, bv, z_prev,
                                      W1, b1, W2, b2, scale,
                                      zbuf, h1buf, ybuf, out, ny, nbp, ctr);
}

// Round 15
// 87.466 us; speedup vs baseline: 2.5330x; 2.0627x over previous
//
#include <hip/hip_runtime.h>
#include <hip/hip_bf16.h>
#include <math.h>

#define C_N 50000

typedef float f32x16 __attribute__((ext_vector_type(16)));
typedef float f32x4v __attribute__((ext_vector_type(4)));
typedef short bf16x8 __attribute__((ext_vector_type(8)));
typedef unsigned short u16x4 __attribute__((ext_vector_type(4)));
#define VZERO16 {0.f,0.f,0.f,0.f,0.f,0.f,0.f,0.f,0.f,0.f,0.f,0.f,0.f,0.f,0.f,0.f}

// ---- ws layout (float offsets, all multiples of 16) ----
#define OQ     0        // Q[1024]
#define OZB    1024     // zbuf[1024]
#define OH1L   2048     // h1low[1024]  (z_prev @ W1[1024:2048])
#define OH1    3072     // h1buf[1024]
#define OYB    4096     // ybuf[1024]
#define OSUMB  5120     // per-block head sums 512*16
#define OQKB   13312    // qkb bf16 B-fragments: 16384 ushort (8192 floats)
#define OPP2   21504    // pp2 bf16: 32*16384 ushort (262144 float slots)
#define OPP    283648   // pool partials, bf16: nb*16384 ushort

__device__ __forceinline__ int brev4(int l){
  return ((l&1)<<3)|((l&2)<<1)|((l&4)>>1)|((l&8)>>3);
}

__device__ __forceinline__ float bf2f(unsigned short u){
  unsigned int x = ((unsigned int)u)<<16;
  return __builtin_bit_cast(float, x);
}

// Sum 16 values (f32x16) over 64 lanes; lanes l<16 get total for head brev4(l).
__device__ __forceinline__ float vred16(f32x16 v, int lane){
  float send, got;
#define RS(A,B,M) \
  send = (lane&M)? v[A] : v[B]; \
  got  = __shfl_xor(send, M);   \
  v[A] = ((lane&M)? v[B] : v[A]) + got;
  RS(0,8,1) RS(1,9,1) RS(2,10,1) RS(3,11,1)
  RS(4,12,1) RS(5,13,1) RS(6,14,1) RS(7,15,1)
  RS(0,4,2) RS(1,5,2) RS(2,6,2) RS(3,7,2)
  RS(0,2,4) RS(1,3,4)
  RS(0,1,8)
#undef RS
  float t = v[0];
  t += __shfl_xor(t,16);
  t += __shfl_xor(t,32);
  return t;
}

// ---- 16-output matvec block, NT threads: out_j = sum_i x[i]*W[i*1024+j] ----
template<int IN, int NT>
__device__ __forceinline__ float mv_dot(const float* __restrict__ W,
    const float* __restrict__ x, int tid, int jblk){
  __shared__ float xs[IN];
  __shared__ float red[NT/16][17];
  for (int k=tid;k<IN;k+=NT) xs[k]=x[k];
  __syncthreads();
  int jq = tid&15, iq = tid>>4;
  int j = jblk*16 + jq;
  float acc = 0.f;
#pragma unroll 8
  for (int i=iq;i<IN;i+=NT/16)
    acc = fmaf(xs[i], W[(size_t)i*1024 + j], acc);
  red[iq][jq] = acc;
  __syncthreads();
  float s = 0.f;
  if (tid < 16){
#pragma unroll
    for (int ii=0;ii<NT/16;ii++) s += red[ii][tid];
  }
  return s;
}

// Q = z_prev@Wq + bq
__global__ __launch_bounds__(1024) void hm_mvQ(const float* __restrict__ W,
    const float* __restrict__ x, const float* __restrict__ bq,
    float* __restrict__ Q){
  float s = mv_dot<1024,1024>(W, x, threadIdx.x, blockIdx.x);
  int tid = threadIdx.x;
  if (tid < 16){
    int j0 = blockIdx.x*16;
    Q[j0+tid] = s + bq[j0+tid];
  }
}

// qk[i][h] = sum_t Wk[i][h*64+t]*Q[h*64+t]; one wave per row i.
// Writes DIRECTLY in bf16 MFMA B-fragment order:
// flat bf16 idx = (kc*64 + rg*16 + h)*8 + jj with kc=i>>5, rg=(i>>3)&3, jj=i&7.
__global__ __launch_bounds__(256) void hm_qk2(const float* __restrict__ Wk,
    const float* __restrict__ Q, unsigned short* __restrict__ qkb){
  __shared__ float qlds[1024];
  int tid = threadIdx.x;
  for (int k=tid;k<1024;k+=256) qlds[k]=Q[k];
  __syncthreads();
  int w = tid>>6, l = tid&63;
  int i = blockIdx.x*4 + w;
  const float* wr = Wk + (size_t)i*1024 + l;
  f32x16 acc = VZERO16;
#define QKS(k) acc[k] = wr[k*64] * qlds[k*64 + l];
  QKS(0) QKS(1) QKS(2) QKS(3) QKS(4) QKS(5) QKS(6) QKS(7)
  QKS(8) QKS(9) QKS(10) QKS(11) QKS(12) QKS(13) QKS(14) QKS(15)
#undef QKS
  float t = vred16(acc, l);
  if (l < 16){
    int h = brev4(l);
    int kc = i>>5, rg = (i>>3)&3, jj = i&7;
    __hip_bfloat16 b = __float2bfloat16(t);
    qkb[(kc*64 + rg*16 + h)*8 + jj] = *(unsigned short*)&b;
  }
}

#define LD2(AP,KC,FA,FB) \
  FA = *(const float4*)((AP)+(KC)*32); \
  FB = *(const float4*)((AP)+(KC)*32+4);
#define CVT8(FA,FB,AV) { \
  __hip_bfloat16 c0=__float2bfloat16(FA.x),c1=__float2bfloat16(FA.y); \
  __hip_bfloat16 c2=__float2bfloat16(FA.z),c3=__float2bfloat16(FA.w); \
  __hip_bfloat16 c4=__float2bfloat16(FB.x),c5=__float2bfloat16(FB.y); \
  __hip_bfloat16 c6=__float2bfloat16(FB.z),c7=__float2bfloat16(FB.w); \
  AV[0]=*(short*)&c0; AV[1]=*(short*)&c1; AV[2]=*(short*)&c2; AV[3]=*(short*)&c3; \
  AV[4]=*(short*)&c4; AV[5]=*(short*)&c5; AV[6]=*(short*)&c6; AV[7]=*(short*)&c7; }

// Fused scores(MFMA)+exp+pool — EXACT R11 structure (87.5us config).
// No epilogue additions: R13 showed extra epilogue state spills the pool
// accumulators (VGPR 215->108, 256us). Global-sync variants cost ~40us per
// barrier (R10 cooperative, R14 hand-rolled) — kernel boundaries stay.
__global__ __launch_bounds__(256,2) void hm_fused(const float* __restrict__ nodes,
    const unsigned short* __restrict__ qkb, unsigned short* __restrict__ parts,
    float* __restrict__ sumpb){
  extern __shared__ float tile[];           // [16][1028]
  __shared__ float part[4][16][17];
  __shared__ float eb[16][16];
  const int tid = threadIdx.x, w = tid>>6, l = tid&63;
  const int rowA = l&15, kgrp = l>>4;
  const int r_ = tid>>4, h_ = tid&15;

  bf16x8 bq0,bq1,bq2,bq3,bq4,bq5,bq6,bq7;
  {
    const bf16x8* qb = (const bf16x8*)qkb;
    const int o = w*8*64 + l;
    bq0=qb[o]; bq1=qb[o+64]; bq2=qb[o+128]; bq3=qb[o+192];
    bq4=qb[o+256]; bq5=qb[o+320]; bq6=qb[o+384]; bq7=qb[o+448];
  }
  f32x16 a0 = VZERO16, a1 = VZERO16, a2 = VZERO16, a3 = VZERO16;
  float ssum = 0.f;
  const int stride = gridDim.x;

  int cb = blockIdx.x;
  float4 p0a,p0b,p1a,p1b,p2a,p2b,p3a,p3b,p4a,p4b,p5a,p5b,p6a,p6b,p7a,p7b;
  {
    const float* ap = nodes + ((size_t)(cb*16 + rowA))*1024 + w*256 + kgrp*8;
    LD2(ap,0,p0a,p0b) LD2(ap,1,p1a,p1b) LD2(ap,2,p2a,p2b) LD2(ap,3,p3a,p3b)
    LD2(ap,4,p4a,p4b) LD2(ap,5,p5a,p5b) LD2(ap,6,p6a,p6b) LD2(ap,7,p7a,p7b)
  }
  float* tw = tile + rowA*1028 + w*256 + kgrp*8;

  for (; cb < 3125; cb += stride){
    *(float4*)(tw+0*32) = p0a; *(float4*)(tw+0*32+4) = p0b;
    *(float4*)(tw+1*32) = p1a; *(float4*)(tw+1*32+4) = p1b;
    *(float4*)(tw+2*32) = p2a; *(float4*)(tw+2*32+4) = p2b;
    *(float4*)(tw+3*32) = p3a; *(float4*)(tw+3*32+4) = p3b;
    *(float4*)(tw+4*32) = p4a; *(float4*)(tw+4*32+4) = p4b;
    *(float4*)(tw+5*32) = p5a; *(float4*)(tw+5*32+4) = p5b;
    *(float4*)(tw+6*32) = p6a; *(float4*)(tw+6*32+4) = p6b;
    *(float4*)(tw+7*32) = p7a; *(float4*)(tw+7*32+4) = p7b;
    bf16x8 av0,av1,av2,av3,av4,av5,av6,av7;
    CVT8(p0a,p0b,av0) CVT8(p1a,p1b,av1) CVT8(p2a,p2b,av2) CVT8(p3a,p3b,av3)
    CVT8(p4a,p4b,av4) CVT8(p5a,p5b,av5) CVT8(p6a,p6b,av6) CVT8(p7a,p7b,av7)
    f32x4v D0 = {0.f,0.f,0.f,0.f};
    f32x4v D1 = {0.f,0.f,0.f,0.f};
    D0 = __builtin_amdgcn_mfma_f32_16x16x32_bf16(av0, bq0, D0, 0,0,0);
    D1 = __builtin_amdgcn_mfma_f32_16x16x32_bf16(av1, bq1, D1, 0,0,0);
    D0 = __builtin_amdgcn_mfma_f32_16x16x32_bf16(av2, bq2, D0, 0,0,0);
    D1 = __builtin_amdgcn_mfma_f32_16x16x32_bf16(av3, bq3, D1, 0,0,0);
    D0 = __builtin_amdgcn_mfma_f32_16x16x32_bf16(av4, bq4, D0, 0,0,0);
    D1 = __builtin_amdgcn_mfma_f32_16x16x32_bf16(av5, bq5, D1, 0,0,0);
    D0 = __builtin_amdgcn_mfma_f32_16x16x32_bf16(av6, bq6, D0, 0,0,0);
    D1 = __builtin_amdgcn_mfma_f32_16x16x32_bf16(av7, bq7, D1, 0,0,0);
    {
      int cbn = cb + stride; if (cbn >= 3125) cbn = cb;
      const float* apn = nodes + ((size_t)(cbn*16 + rowA))*1024 + w*256 + kgrp*8;
      LD2(apn,0,p0a,p0b) LD2(apn,1,p1a,p1b) LD2(apn,2,p2a,p2b) LD2(apn,3,p3a,p3b)
      LD2(apn,4,p4a,p4b) LD2(apn,5,p5a,p5b) LD2(apn,6,p6a,p6b) LD2(apn,7,p7a,p7b)
    }
#pragma unroll
    for (int i=0;i<4;i++) part[w][kgrp*4+i][rowA] = D0[i] + D1[i];
    __syncthreads();                       // barrier1: part ready
    {
      float s = part[0][r_][h_]+part[1][r_][h_]+part[2][r_][h_]+part[3][r_][h_];
      eb[r_][h_] = __expf(s * 0.125f);
    }
    __syncthreads();                       // barrier2: eb ready
    if (tid < 16){
#pragma unroll
      for (int rr=0;rr<16;rr++) ssum += eb[rr][tid];
    }
    const float* tr = tile + w*256 + l*4;
#pragma unroll 4
    for (int r=0;r<16;r++){
      float4 nv = *(const float4*)(tr + r*1028);
      f32x16 u = *(const f32x16*)&eb[r][0];
      a0 += u*nv.x; a1 += u*nv.y; a2 += u*nv.z; a3 += u*nv.w;
    }
  }
  unsigned short* p = parts + (size_t)blockIdx.x*16384 + w*256 + l*4;
#pragma unroll
  for (int h=0;h<16;h++){
    __hip_bfloat16 b0=__float2bfloat16(a0[h]), b1=__float2bfloat16(a1[h]);
    __hip_bfloat16 b2=__float2bfloat16(a2[h]), b3=__float2bfloat16(a3[h]);
    u16x4 o;
    o[0]=*(unsigned short*)&b0; o[1]=*(unsigned short*)&b1;
    o[2]=*(unsigned short*)&b2; o[3]=*(unsigned short*)&b3;
    *(u16x4*)(p + h*1024) = o;
  }
  if (tid < 16) sumpb[blockIdx.x*16 + tid] = ssum;
}

// Stage A: pp2[y][j] = sum of 16 bf16 partials; u16x4 per thread (8B loads)
__global__ __launch_bounds__(256) void hm_predA(const unsigned short* __restrict__ parts,
    unsigned short* __restrict__ pp2, int nb){
  int j4 = blockIdx.x*256 + threadIdx.x;
  int b0 = blockIdx.y*16;
  int b1 = b0+16 < nb ? b0+16 : nb;
  float s0=0.f, s1=0.f, s2=0.f, s3=0.f;
  for (int b=b0;b<b1;b++){
    u16x4 v = *(const u16x4*)&parts[(size_t)b*16384 + j4*4];
    s0 += bf2f(v[0]); s1 += bf2f(v[1]); s2 += bf2f(v[2]); s3 += bf2f(v[3]);
  }
  __hip_bfloat16 r0=__float2bfloat16(s0), r1=__float2bfloat16(s1);
  __hip_bfloat16 r2=__float2bfloat16(s2), r3=__float2bfloat16(s3);
  u16x4 o;
  o[0]=*(unsigned short*)&r0; o[1]=*(unsigned short*)&r1;
  o[2]=*(unsigned short*)&r2; o[3]=*(unsigned short*)&r3;
  *(u16x4*)&pp2[(size_t)blockIdx.y*16384 + j4*4] = o;
}

// Grid (64,2): y=0 -> zbuf[j] = (Pu[hh]·Wv[:,j])/S[h] + bv[j]  (R11 mvV body);
// y=1 -> h1low[j] = z_prev·W1[1024:2048][:,j]  (independent of attention —
// runs concurrently, removing 4MB from the serial chain).
__global__ __launch_bounds__(1024) void hm_mvV(const float* __restrict__ Wv,
    const unsigned short* __restrict__ pp2, const float* __restrict__ sumpb,
    const float* __restrict__ bv, const float* __restrict__ z_prev,
    const float* __restrict__ W1, float* __restrict__ zbuf,
    float* __restrict__ h1low, int ny, int nb){
  __shared__ float xs[1024];
  __shared__ float red[64][17];
  __shared__ float ssl[16];
  const int tid = threadIdx.x;
  const int jq = tid&15, iq = tid>>4;
  if (blockIdx.y == 0){
    const int hh = blockIdx.x>>2;
    float sacc = 0.f;
    for (int b=tid; b<nb; b+=1024) sacc += sumpb[b*16 + hh];
#pragma unroll
    for (int m=1;m<64;m<<=1) sacc += __shfl_xor(sacc, m);
    if ((tid&63)==0) ssl[tid>>6] = sacc;
    float s = 0.f;
    for (int y=0;y<ny;y++) s += bf2f(pp2[(size_t)y*16384 + hh*1024 + tid]);
    xs[tid] = s;
    __syncthreads();
    int j = blockIdx.x*16 + jq;
    float acc = 0.f;
#pragma unroll 8
    for (int i=iq;i<1024;i+=64)
      acc = fmaf(xs[i], Wv[(size_t)i*1024 + j], acc);
    red[iq][jq] = acc;
    __syncthreads();
    if (tid < 16){
      float s2 = 0.f;
#pragma unroll
      for (int ii=0;ii<64;ii++) s2 += red[ii][tid];
      float S = 0.f;
#pragma unroll
      for (int q=0;q<16;q++) S += ssl[q];
      int jo = blockIdx.x*16 + tid;
      zbuf[jo] = s2 / S + bv[jo];
    }
  } else {
    xs[tid] = z_prev[tid];
    __syncthreads();
    int j = blockIdx.x*16 + jq;
    const float* Wp = W1 + (size_t)1024*1024;   // lower half rows
    float acc = 0.f;
#pragma unroll 8
    for (int i=iq;i<1024;i+=64)
      acc = fmaf(xs[i], Wp[(size_t)i*1024 + j], acc);
    red[iq][jq] = acc;
    __syncthreads();
    if (tid < 16){
      float s = 0.f;
#pragma unroll
      for (int ii=0;ii<64;ii++) s += red[ii][tid];
      h1low[blockIdx.x*16 + tid] = s;
    }
  }
}

// h1 = GELU(zbuf·W1[0:1024] + h1low + b1) — upper half only (4MB).
__global__ __launch_bounds__(1024) void hm_mvW1u(const float* __restrict__ W1,
    const float* __restrict__ zbuf, const float* __restrict__ h1low,
    const float* __restrict__ b1, float* __restrict__ h1buf){
  float s = mv_dot<1024,1024>(W1, zbuf, threadIdx.x, blockIdx.x);
  int tid = threadIdx.x;
  if (tid < 16){
    int jo = blockIdx.x*16 + tid;
    float v = s + h1low[jo] + b1[jo];
    h1buf[jo] = 0.5f * v * (1.0f + erff(v * 0.70710678118654752f));
  }
}

// y = h1·W2 + b2
__global__ __launch_bounds__(1024) void hm_mvW2(const float* __restrict__ W2,
    const float* __restrict__ h1buf, const float* __restrict__ b2,
    float* __restrict__ ybuf){
  float s = mv_dot<1024,1024>(W2, h1buf, threadIdx.x, blockIdx.x);
  int tid = threadIdx.x;
  if (tid < 16){
    int jo = blockIdx.x*16 + tid;
    ybuf[jo] = s + b2[jo];
  }
}

__global__ __launch_bounds__(256) void hm_rms(const float* __restrict__ y,
    const float* __restrict__ scale, float* __restrict__ out){
  __shared__ float red[4];
  __shared__ float msv;
  int tid = threadIdx.x;
  float local = 0.f;
  for (int j=tid;j<1024;j+=256){ float t = y[j]; local = fmaf(t,t,local); }
#pragma unroll
  for (int m=1;m<64;m<<=1) local += __shfl_xor(local, m);
  if ((tid&63)==0) red[tid>>6] = local;
  __syncthreads();
  if (tid==0){
    float s = red[0]+red[1]+red[2]+red[3];
    msv = rsqrtf(s*(1.0f/1024.0f) + 1e-6f);
  }
  __syncthreads();
  float r = msv;
  for (int j=tid;j<1024;j+=256) out[j] = scale[j]*y[j]*r;
}

extern "C" void kernel_launch(void* const* d_in, const int* in_sizes, int n_in,
                              void* d_out, int out_size, void* d_ws, size_t ws_size,
                              hipStream_t stream){
  const float* nodes  = (const float*)d_in[0];
  const float* z_prev = (const float*)d_in[1];
  const float* Wq = (const float*)d_in[2];
  const float* bq = (const float*)d_in[3];
  const float* Wk = (const float*)d_in[4];
  // d_in[5] = bk — cancels in softmax, unused
  const float* Wv = (const float*)d_in[6];
  const float* bv = (const float*)d_in[7];
  const float* W1 = (const float*)d_in[8];
  const float* b1 = (const float*)d_in[9];
  const float* W2 = (const float*)d_in[10];
  const float* b2 = (const float*)d_in[11];
  const float* scale = (const float*)d_in[12];
  float* ws  = (float*)d_ws;
  float* out = (float*)d_out;

  float* Qv     = ws + OQ;
  float* zbuf   = ws + OZB;
  float* h1low  = ws + OH1L;
  float* h1buf  = ws + OH1;
  float* ybuf   = ws + OYB;
  float* sumb   = ws + OSUMB;
  unsigned short* qkb = (unsigned short*)(ws + OQKB);
  unsigned short* pp2 = (unsigned short*)(ws + OPP2);
  unsigned short* pp  = (unsigned short*)(ws + OPP);

  size_t need0 = (size_t)OPP*4;
  int nbp = 1;
  if (ws_size > need0 + 32768) nbp = (int)((ws_size - need0)/32768);
  if (nbp > 512) nbp = 512;
  if (nbp < 1) nbp = 1;
  int ny = (nbp + 15)/16;   // <= 32

  const size_t tile_bytes = 16*1028*sizeof(float);  // 65792

  hm_mvQ   <<<64,  1024, 0, stream>>>(Wq, z_prev, bq, Qv);
  hm_qk2   <<<256, 256, 0, stream>>>(Wk, Qv, qkb);
  hm_fused <<<nbp, 256, tile_bytes, stream>>>(nodes, qkb, pp, sumb);
  hm_predA <<<dim3(16,ny), 256, 0, stream>>>(pp, pp2, nbp);
  hm_mvV   <<<dim3(64,2), 1024, 0, stream>>>(Wv, pp2, sumb, bv, z_prev, W1,
                                             zbuf, h1low, ny, nbp);
  hm_mvW1u <<<64,  1024, 0, stream>>>(W1, zbuf, h1low, b1, h1buf);
  hm_mvW2  <<<64,  1024, 0, stream>>>(W2, h1buf, b2, ybuf);
  hm_rms   <<<1,   256, 0, stream>>>(ybuf, scale, out);
}